// Round 1
// baseline (370.342 us; speedup 1.0000x reference)
//
#include <hip/hip_runtime.h>
#include <math.h>

#define BB 8
#define NN 512
#define CC 768
#define HH 12
#define HD 64
#define TOPK 90
#define QKV_ELEMS (BB*HH*NN*HD)   // 3145728 elements per q/k/v tensor
#define KC 2304                   // split-K: 3*768

typedef __attribute__((ext_vector_type(8))) short short8;   // 8 bf16 = 4 VGPR
typedef __attribute__((ext_vector_type(4))) float floatx4;  // MFMA C/D

__device__ inline unsigned short f2bf(float f) {
    unsigned int u = __float_as_uint(f);
    u += 0x7FFFu + ((u >> 16) & 1u);           // RNE
    return (unsigned short)(u >> 16);
}
__device__ inline float bf2f(unsigned short h) {
    return __uint_as_float(((unsigned int)h) << 16);
}

// ---------------------------------------------------------------------------
// 16-lane (quad) reductions via DPP row_ror — VALU-only, no LDS pipe.
// row_ror:N ctrl = 0x120|N; rows of 16 lanes match our quad = lane>>4 groups.
// After ror 1,2,4,8 accumulation every lane holds the full 16-lane result.
// ---------------------------------------------------------------------------
template<int CTRL>
__device__ __forceinline__ int dpp_i(int v) {
    return __builtin_amdgcn_update_dpp(0, v, CTRL, 0xF, 0xF, true);
}
#define ROR1 0x121
#define ROR2 0x122
#define ROR4 0x124
#define ROR8 0x128

__device__ __forceinline__ int red_sum16i(int v) {
    v += dpp_i<ROR1>(v); v += dpp_i<ROR2>(v);
    v += dpp_i<ROR4>(v); v += dpp_i<ROR8>(v);
    return v;
}
__device__ __forceinline__ float red_sum16f(float v) {
    v += __int_as_float(dpp_i<ROR1>(__float_as_int(v)));
    v += __int_as_float(dpp_i<ROR2>(__float_as_int(v)));
    v += __int_as_float(dpp_i<ROR4>(__float_as_int(v)));
    v += __int_as_float(dpp_i<ROR8>(__float_as_int(v)));
    return v;
}
__device__ __forceinline__ unsigned int red_or16(unsigned int v) {
    v |= (unsigned int)dpp_i<ROR1>((int)v); v |= (unsigned int)dpp_i<ROR2>((int)v);
    v |= (unsigned int)dpp_i<ROR4>((int)v); v |= (unsigned int)dpp_i<ROR8>((int)v);
    return v;
}
__device__ __forceinline__ unsigned int red_and16(unsigned int v) {
    v &= (unsigned int)dpp_i<ROR1>((int)v); v &= (unsigned int)dpp_i<ROR2>((int)v);
    v &= (unsigned int)dpp_i<ROR4>((int)v); v &= (unsigned int)dpp_i<ROR8>((int)v);
    return v;
}
__device__ __forceinline__ unsigned int red_min16u(unsigned int v) {
    unsigned int t;
    t = (unsigned int)dpp_i<ROR1>((int)v); v = v < t ? v : t;
    t = (unsigned int)dpp_i<ROR2>((int)v); v = v < t ? v : t;
    t = (unsigned int)dpp_i<ROR4>((int)v); v = v < t ? v : t;
    t = (unsigned int)dpp_i<ROR8>((int)v); v = v < t ? v : t;
    return v;
}
__device__ __forceinline__ unsigned int red_max16u(unsigned int v) {
    unsigned int t;
    t = (unsigned int)dpp_i<ROR1>((int)v); v = v > t ? v : t;
    t = (unsigned int)dpp_i<ROR2>((int)v); v = v > t ? v : t;
    t = (unsigned int)dpp_i<ROR4>((int)v); v = v > t ? v : t;
    t = (unsigned int)dpp_i<ROR8>((int)v); v = v > t ? v : t;
    return v;
}

// ---------------------------------------------------------------------------
// Split kernels: fp32 [rows][768] -> bf16 [rows][2304].
// IS_A: blocks [hi | hi | lo]; !IS_A: blocks [hi | lo | hi]  (hh+hl+lh).
// ---------------------------------------------------------------------------
template<bool IS_A>
__global__ __launch_bounds__(256) void split_k(const float* __restrict__ in,
                                               unsigned short* __restrict__ o2,
                                               int total) {
    int idx = blockIdx.x * 256 + threadIdx.x;
    if (idx >= total) return;
    int e = idx * 4;
    int m = e / CC, kk = e - m * CC;
    float4 f = *(const float4*)(in + e);
    ushort4 hi, lo;
    hi.x = f2bf(f.x); lo.x = f2bf(f.x - bf2f(hi.x));
    hi.y = f2bf(f.y); lo.y = f2bf(f.y - bf2f(hi.y));
    hi.z = f2bf(f.z); lo.z = f2bf(f.z - bf2f(hi.z));
    hi.w = f2bf(f.w); lo.w = f2bf(f.w - bf2f(hi.w));
    unsigned short* base = o2 + (size_t)m * KC + kk;
    *(ushort4*)(base)        = hi;
    *(ushort4*)(base + CC)   = IS_A ? hi : lo;
    *(ushort4*)(base + 2*CC) = IS_A ? lo : hi;
}

// ---------------------------------------------------------------------------
// Split-bf16 MFMA GEMM, BK=64 (32 MFMA per barrier-pair, 36 iters).
// QKV_EPI: q,k -> split bf16 planes [B,H,N,hd]; v -> split bf16 TRANSPOSED
// planes vth/vtl [B,H,hd,N].  Else: out[m][NCOLS] + bias.
// ---------------------------------------------------------------------------
template<int NCOLS, bool QKV_EPI>
__global__ __launch_bounds__(256) void gemm_split(const unsigned short* __restrict__ A,
                                                  const unsigned short* __restrict__ Bm,
                                                  const float* __restrict__ bias,
                                                  float* __restrict__ out,
                                                  unsigned short* __restrict__ qh,
                                                  unsigned short* __restrict__ ql,
                                                  unsigned short* __restrict__ kh,
                                                  unsigned short* __restrict__ kl,
                                                  unsigned short* __restrict__ vth,
                                                  unsigned short* __restrict__ vtl) {
    __shared__ char lds[32768];          // A tile 16KB @0, B tile 16KB @16384
    const int bm = blockIdx.x, bn = blockIdx.y;
    const int tid  = threadIdx.x;
    const int wave = tid >> 6, lane = tid & 63;
    const int wm = wave >> 1, wn = wave & 1;
    const int quad = lane >> 4, r = lane & 15;

    // staging pointers: inst i, chunk c = tid + i*256 (c in [0,2048));
    // matrix = c>>10; s = c&1023; m = s>>3; octp = s&7; oct = octp ^ (m&7)
    const unsigned short* gbase[8];
#pragma unroll
    for (int i = 0; i < 8; ++i) {
        int c = tid + i*256;
        int s = c & 1023;
        int m = s >> 3, octp = s & 7, oct = octp ^ (m & 7);
        gbase[i] = (i < 4 ? A  + (size_t)(bm*128 + m) * KC
                          : Bm + (size_t)(bn*128 + m) * KC) + oct*8;
    }

    // fragment LDS offsets: row stored as 8 octets of 16B, oct = kslot ^ (row&7)
    int aoff[2][4], boff[2][4];
#pragma unroll
    for (int kb = 0; kb < 2; ++kb)
#pragma unroll
        for (int i = 0; i < 4; ++i) {
            int ra = wm*64 + i*16 + r;
            int rb2 = wn*64 + i*16 + r;
            aoff[kb][i] = (ra*8 + ((kb*4 + quad) ^ (ra & 7))) * 16;
            boff[kb][i] = 16384 + (rb2*8 + ((kb*4 + quad) ^ (rb2 & 7))) * 16;
        }

    floatx4 acc[4][4];
#pragma unroll
    for (int i = 0; i < 4; ++i)
#pragma unroll
        for (int j = 0; j < 4; ++j)
            acc[i][j] = (floatx4){0.f, 0.f, 0.f, 0.f};

    for (int it = 0; it < KC/64; ++it) {
        __syncthreads();
#pragma unroll
        for (int i = 0; i < 8; ++i) {
            __builtin_amdgcn_global_load_lds(
                (const __attribute__((address_space(1))) unsigned int*)gbase[i],
                (__attribute__((address_space(3))) unsigned int*)(lds + i*4096 + wave*1024),
                16, 0, 0);
            gbase[i] += 64;
        }
        asm volatile("s_waitcnt vmcnt(0)" ::: "memory");
        __syncthreads();

#pragma unroll
        for (int kb = 0; kb < 2; ++kb) {
            short8 af[4], bf[4];
#pragma unroll
            for (int i = 0; i < 4; ++i) af[i] = *(const short8*)(lds + aoff[kb][i]);
#pragma unroll
            for (int j = 0; j < 4; ++j) bf[j] = *(const short8*)(lds + boff[kb][j]);
#pragma unroll
            for (int i = 0; i < 4; ++i)
#pragma unroll
                for (int j = 0; j < 4; ++j)
                    acc[i][j] = __builtin_amdgcn_mfma_f32_16x16x32_bf16(af[i], bf[j], acc[i][j], 0, 0, 0);
        }
    }

    if (QKV_EPI) {
#pragma unroll
        for (int j = 0; j < 4; ++j) {
            int col = bn*128 + wn*64 + j*16 + r;     // [0,2304)
            int t = col / CC;
            int rem = col - t*CC;
            int h = rem >> 6, d = rem & 63;
            if (t == 2) {
                // v transposed split: vth/vtl[(bh*64+d)*512 + n], ushort4 over 4 rows
#pragma unroll
                for (int i = 0; i < 4; ++i) {
                    int m0 = bm*128 + wm*64 + i*16 + quad*4;
                    int b = m0 >> 9, n0 = m0 & 511;
                    ushort4 hi, lo;
                    hi.x = f2bf(acc[i][j][0]); lo.x = f2bf(acc[i][j][0] - bf2f(hi.x));
                    hi.y = f2bf(acc[i][j][1]); lo.y = f2bf(acc[i][j][1] - bf2f(hi.y));
                    hi.z = f2bf(acc[i][j][2]); lo.z = f2bf(acc[i][j][2] - bf2f(hi.z));
                    hi.w = f2bf(acc[i][j][3]); lo.w = f2bf(acc[i][j][3] - bf2f(hi.w));
                    size_t off = ((size_t)((b*HH + h)*HD + d))*NN + n0;
                    *(ushort4*)(vth + off) = hi;
                    *(ushort4*)(vtl + off) = lo;
                }
            } else {
                unsigned short* ph = (t == 0) ? qh : kh;
                unsigned short* pl = (t == 0) ? ql : kl;
#pragma unroll
                for (int i = 0; i < 4; ++i) {
#pragma unroll
                    for (int e = 0; e < 4; ++e) {
                        int m = bm*128 + wm*64 + i*16 + quad*4 + e;
                        int b = m >> 9, nrow = m & 511;
                        size_t idx = ((size_t)(b*HH + h)*NN + nrow)*HD + d;
                        float val = acc[i][j][e];
                        unsigned short hi = f2bf(val);
                        ph[idx] = hi;
                        pl[idx] = f2bf(val - bf2f(hi));
                    }
                }
            }
        }
    } else {
#pragma unroll
        for (int j = 0; j < 4; ++j) {
            int col = bn*128 + wn*64 + j*16 + r;
            float bv = bias[col];
#pragma unroll
            for (int i = 0; i < 4; ++i) {
#pragma unroll
                for (int e = 0; e < 4; ++e) {
                    int m = bm*128 + wm*64 + i*16 + quad*4 + e;
                    out[(size_t)m*NCOLS + col] = acc[i][j][e] + bv;
                }
            }
        }
    }
}

// ---------------------------------------------------------------------------
// FUSED: MFMA scores + exact top-k + softmax + PV.
// Phase 2 (this round): all 16-lane reductions moved from __shfl_xor
// (ds_swizzle, LDS pipe, ~30-60cy dependent latency) to DPP row_ror VALU
// reductions; keys built from RAW scores (x0.125 is a monotone pow2 map,
// order/ties unchanged); softmax values taken from live acc regs with the
// scale folded into the exp argument (drops the 3-op key decode).
// ---------------------------------------------------------------------------
__global__ __launch_bounds__(256, 1) void attn_scores_k(
        const unsigned short* __restrict__ qh, const unsigned short* __restrict__ ql,
        const unsigned short* __restrict__ kh, const unsigned short* __restrict__ kl,
        const unsigned short* __restrict__ vth, const unsigned short* __restrict__ vtl,
        const int* __restrict__ islast, float* __restrict__ attn,
        unsigned short* __restrict__ Ao) {

    __shared__ char smem[34816];
    // phase 0/1: qs = ushort[2][64][72] @0 (18432 B); ks @18432 (16384 B)
    // phase 3:   pls = ushort[64][80] @0 (10240 B); vhs @10240; vls @18432 (8192 each)
    unsigned short* qs = (unsigned short*)smem;
    char* ks = smem + 18432;

    const int bh = blockIdx.x % 96;
    const int rb = blockIdx.x / 96;
    const int tid = threadIdx.x;
    const int wv = tid >> 6, lane = tid & 63;
    const int quad = lane >> 4, r = lane & 15;
    const int b = bh / HH, h = bh % HH;

    const unsigned short* gq[2] = { qh + ((size_t)bh*NN + rb*64)*HD,
                                    ql + ((size_t)bh*NN + rb*64)*HD };
#pragma unroll
    for (int i = 0; i < 4; ++i) {
        int s = tid + i*256;
        int hl = s >> 9, s2 = s & 511;
        int row = s2 >> 3, oct = s2 & 7;
        short8 val = *(const short8*)(gq[hl] + row*HD + oct*8);
        *(short8*)&qs[(hl*64 + row)*72 + oct*8] = val;
    }
    __syncthreads();

    short8 afr[6];
    {
        const int arow = wv*16 + r;
#pragma unroll
        for (int t = 0; t < 3; ++t) {
            int src = (t == 2) ? 1 : 0;
#pragma unroll
            for (int half = 0; half < 2; ++half)
                afr[t*2+half] = *(const short8*)&qs[(src*64 + arow)*72 + half*32 + quad*8];
        }
    }

    floatx4 acc[32];
#pragma unroll
    for (int ct = 0; ct < 32; ++ct) acc[ct] = (floatx4){0.f,0.f,0.f,0.f};

    const unsigned short* gk[2] = { kh + (size_t)bh*NN*HD, kl + (size_t)bh*NN*HD };

    for (int ch = 0; ch < 8; ++ch) {
        __syncthreads();
#pragma unroll
        for (int i = 0; i < 4; ++i) {
            int s = tid + i*256;
            int hl = s >> 9, s2 = s & 511;
            int row = s2 >> 3, octp = s2 & 7;
            int oct = octp ^ (row & 7);
            const unsigned short* src = gk[hl] + (size_t)(ch*64 + row)*HD + oct*8;
            __builtin_amdgcn_global_load_lds(
                (const __attribute__((address_space(1))) unsigned int*)src,
                (__attribute__((address_space(3))) unsigned int*)(ks + (size_t)(i*256 + wv*64)*16),
                16, 0, 0);
        }
        asm volatile("s_waitcnt vmcnt(0)" ::: "memory");
        __syncthreads();

#pragma unroll
        for (int ctl = 0; ctl < 4; ++ctl) {
            const int ct = ch*4 + ctl;
            const int n = ctl*16 + r;
#pragma unroll
            for (int t = 0; t < 3; ++t) {
                const int srcB = (t == 1) ? 1 : 0;
#pragma unroll
                for (int half = 0; half < 2; ++half) {
                    const int oct = (half*4 + quad) ^ (n & 7);
                    short8 bfr = *(const short8*)(ks + srcB*8192 + n*128 + oct*16);
                    acc[ct] = __builtin_amdgcn_mfma_f32_16x16x32_bf16(afr[t*2+half], bfr, acc[ct], 0, 0, 0);
                }
            }
        }
    }

    const int lastv = islast[0];

    // ---- phase 2: per reg-row e: exact top-k (register radix) + softmax ----
#pragma unroll
    for (int e = 0; e < 4; ++e) {
        unsigned int key[32];
#pragma unroll
        for (int ct = 0; ct < 32; ++ct) {
            unsigned int t = __float_as_uint(acc[ct][e]);
            // monotone map: order/ties identical to the x0.125-scaled domain
            key[ct] = t ^ (unsigned int)(((int)t >> 31) | (int)0x80000000);
        }

        unsigned int kth = 0u;
        if (!lastv) {
            unsigned int uo = key[0], ua = key[0];
#pragma unroll
            for (int ct = 1; ct < 32; ++ct) { uo |= key[ct]; ua &= key[ct]; }
            uo = red_or16(uo);
            ua = red_and16(ua);
            unsigned int diff = uo ^ ua;
            int bit = 31 - __clz(diff);
            unsigned int am = 0xFFFFFFFFu;
            int kk = TOPK, cntA = 512;
            int done = (diff == 0u);
            while (__ballot(!done) != 0ull) {
                if (!done) {
                    unsigned int m1 = 0u;
#pragma unroll
                    for (int ct = 0; ct < 32; ++ct)
                        m1 |= ((key[ct] >> bit) & 1u) << ct;
                    int c1 = __popc(am & m1);
                    c1 = red_sum16i(c1);
                    if (kk <= c1) { am &= m1; cntA = c1; }
                    else          { kk -= c1; am &= ~m1; cntA -= c1; }
                    --bit;
                    done = (cntA == kk) | (kk == 1) | (bit < 0);
                }
            }
            unsigned int mn = 0xFFFFFFFFu, mx = 0u;
#pragma unroll
            for (int ct = 0; ct < 32; ++ct) {
                if ((am >> ct) & 1u) {
                    mn = mn < key[ct] ? mn : key[ct];
                    mx = mx > key[ct] ? mx : key[ct];
                }
            }
            mn = red_min16u(mn);
            mx = red_max16u(mx);
            kth = (kk == 1) ? mx : mn;
        }

        unsigned int umx = key[0];
#pragma unroll
        for (int ct = 1; ct < 32; ++ct) umx = umx > key[ct] ? umx : key[ct];
        umx = red_max16u(umx);
        float fmx = __uint_as_float((umx & 0x80000000u) ? (umx & 0x7FFFFFFFu) : ~umx);

        float sum = 0.f;
#pragma unroll
        for (int ct = 0; ct < 32; ++ct) {
            float f = acc[ct][e];                 // raw score, still live
            float ev = (lastv || key[ct] >= kth) ? __expf((f - fmx) * 0.125f) : 0.f;
            acc[ct][e] = ev;
            sum += ev;
        }
        sum = red_sum16f(sum);
        const float inv = 1.f / sum;
        float* arow = attn + ((size_t)bh*NN + rb*64 + wv*16 + quad*4 + e) * NN;
#pragma unroll
        for (int ct = 0; ct < 32; ++ct) {
            float p = acc[ct][e] * inv;
            acc[ct][e] = p;                  // keep normalized P in regs for PV
            arow[ct*16 + r] = p;
        }
    }

    // ---- phase 3: O = P @ V  (P in acc regs; 8 chunks of 64 K-cols) ----
    unsigned short* pls = (unsigned short*)smem;   // [64][80]
    char* vhs = smem + 10240;
    char* vls = smem + 18432;
    const unsigned short* gvh = vth + (size_t)bh*HD*NN;
    const unsigned short* gvl = vtl + (size_t)bh*HD*NN;

    floatx4 accO[4];
#pragma unroll
    for (int j = 0; j < 4; ++j) accO[j] = (floatx4){0.f,0.f,0.f,0.f};

    for (int ch = 0; ch < 8; ++ch) {
        __syncthreads();   // prev chunk reads done (first iter: phases 0-2 done)
        // write this wave's 16x64 P chunk as bf16 (C-layout -> [row][col])
#pragma unroll
        for (int ctl = 0; ctl < 4; ++ctl) {
            int col = ctl*16 + r;
#pragma unroll
            for (int e = 0; e < 4; ++e)
                pls[(wv*16 + quad*4 + e)*80 + col] = f2bf(acc[ch*4 + ctl][e]);
        }
        // stage V^T chunk (rows d=0..63, cols m=ch*64..+63), hi+lo planes
#pragma unroll
        for (int i = 0; i < 2; ++i) {
            int s = tid + i*256;
            int d = s >> 3, octp = s & 7, oct = octp ^ (d & 7);
            size_t goff = (size_t)d*NN + ch*64 + oct*8;
            __builtin_amdgcn_global_load_lds(
                (const __attribute__((address_space(1))) unsigned int*)(gvh + goff),
                (__attribute__((address_space(3))) unsigned int*)(vhs + (i*256 + wv*64)*16),
                16, 0, 0);
            __builtin_amdgcn_global_load_lds(
                (const __attribute__((address_space(1))) unsigned int*)(gvl + goff),
                (__attribute__((address_space(3))) unsigned int*)(vls + (i*256 + wv*64)*16),
                16, 0, 0);
        }
        asm volatile("s_waitcnt vmcnt(0)" ::: "memory");
        __syncthreads();

#pragma unroll
        for (int kb = 0; kb < 2; ++kb) {
            short8 af = *(const short8*)&pls[(wv*16 + r)*80 + kb*32 + quad*8];
#pragma unroll
            for (int j = 0; j < 4; ++j) {
                int d = j*16 + r;
                int oct = (kb*4 + quad) ^ (d & 7);
                short8 bh8 = *(const short8*)(vhs + d*128 + oct*16);
                short8 bl8 = *(const short8*)(vls + d*128 + oct*16);
                accO[j] = __builtin_amdgcn_mfma_f32_16x16x32_bf16(af, bh8, accO[j], 0, 0, 0);
                accO[j] = __builtin_amdgcn_mfma_f32_16x16x32_bf16(af, bl8, accO[j], 0, 0, 0);
            }
        }
    }

    // ---- epilogue: split-bf16 o [hi|hi|lo] into Ao ----
#pragma unroll
    for (int j = 0; j < 4; ++j) {
        int d = j*16 + r;
#pragma unroll
        for (int e = 0; e < 4; ++e) {
            int n = rb*64 + wv*16 + quad*4 + e;
            size_t mrow = (size_t)b*NN + n;
            float val = accO[j][e];
            unsigned short hi = f2bf(val);
            unsigned short lo = f2bf(val - bf2f(hi));
            unsigned short* base = Ao + mrow*KC + h*HD + d;
            base[0] = hi; base[CC] = hi; base[2*CC] = lo;
        }
    }
}

// ---------------------------------------------------------------------------
extern "C" void kernel_launch(void* const* d_in, const int* in_sizes, int n_in,
                              void* d_out, int out_size, void* d_ws, size_t ws_size,
                              hipStream_t stream) {
    const float* x      = (const float*)d_in[0];
    const float* qkv_w  = (const float*)d_in[1];
    const float* proj_w = (const float*)d_in[2];
    const float* proj_b = (const float*)d_in[3];
    const int*   islast = (const int*)d_in[4];

    float* out  = (float*)d_out;                       // [B,N,C]
    float* attn = out + (size_t)BB*NN*CC;              // [B,H,N,N]

    unsigned short* us = (unsigned short*)d_ws;
    unsigned short* vth = us;                          // [B,H,hd,N] bf16 hi
    unsigned short* vtl = vth + (size_t)QKV_ELEMS;     // [B,H,hd,N] bf16 lo
    unsigned short* qhp = vtl + (size_t)QKV_ELEMS;
    unsigned short* qlp = qhp + (size_t)QKV_ELEMS;
    unsigned short* khp = qlp + (size_t)QKV_ELEMS;
    unsigned short* klp = khp + (size_t)QKV_ELEMS;
    unsigned short* Asp   = klp + (size_t)QKV_ELEMS;   // [4096][2304]
    unsigned short* Bqkv  = Asp  + (size_t)4096*KC;    // [2304][2304]
    unsigned short* Bproj = Bqkv + (size_t)2304*KC;    // [768][2304]

    split_k<true> <<<dim3(4096*CC/4/256), 256, 0, stream>>>(x,      Asp,   4096*CC/4);
    split_k<false><<<dim3(2304*CC/4/256), 256, 0, stream>>>(qkv_w,  Bqkv,  2304*CC/4);
    split_k<false><<<dim3(CC*CC/4/256),   256, 0, stream>>>(proj_w, Bproj, CC*CC/4);

    gemm_split<0, true>  <<<dim3(32, 18), 256, 0, stream>>>(Asp, Bqkv, nullptr, nullptr,
                                                            qhp, qlp, khp, klp, vth, vtl);
    attn_scores_k        <<<dim3(96*8),   256, 0, stream>>>(qhp, qlp, khp, klp, vth, vtl,
                                                            islast, attn, Asp);
    gemm_split<CC, false><<<dim3(32, 6),  256, 0, stream>>>(Asp, Bproj, proj_b, out,
                                                            nullptr, nullptr, nullptr, nullptr,
                                                            nullptr, nullptr);
}

// Round 3
// 362.001 us; speedup vs baseline: 1.0230x; 1.0230x over previous
//
#include <hip/hip_runtime.h>
#include <math.h>

#define BB 8
#define NN 512
#define CC 768
#define HH 12
#define HD 64
#define TOPK 90
#define QKV_ELEMS (BB*HH*NN*HD)   // 3145728 elements per q/k/v tensor
#define KC 2304                   // split-K: 3*768

typedef __attribute__((ext_vector_type(8))) short short8;   // 8 bf16 = 4 VGPR
typedef __attribute__((ext_vector_type(4))) float floatx4;  // MFMA C/D

__device__ inline unsigned short f2bf(float f) {
    unsigned int u = __float_as_uint(f);
    u += 0x7FFFu + ((u >> 16) & 1u);           // RNE
    return (unsigned short)(u >> 16);
}
__device__ inline float bf2f(unsigned short h) {
    return __uint_as_float(((unsigned int)h) << 16);
}

// ---------------------------------------------------------------------------
// Split kernels: fp32 [rows][768] -> bf16 [rows][2304].
// IS_A: blocks [hi | hi | lo]; !IS_A: blocks [hi | lo | hi]  (hh+hl+lh).
// ---------------------------------------------------------------------------
template<bool IS_A>
__global__ __launch_bounds__(256) void split_k(const float* __restrict__ in,
                                               unsigned short* __restrict__ o2,
                                               int total) {
    int idx = blockIdx.x * 256 + threadIdx.x;
    if (idx >= total) return;
    int e = idx * 4;
    int m = e / CC, kk = e - m * CC;
    float4 f = *(const float4*)(in + e);
    ushort4 hi, lo;
    hi.x = f2bf(f.x); lo.x = f2bf(f.x - bf2f(hi.x));
    hi.y = f2bf(f.y); lo.y = f2bf(f.y - bf2f(hi.y));
    hi.z = f2bf(f.z); lo.z = f2bf(f.z - bf2f(hi.z));
    hi.w = f2bf(f.w); lo.w = f2bf(f.w - bf2f(hi.w));
    unsigned short* base = o2 + (size_t)m * KC + kk;
    *(ushort4*)(base)        = hi;
    *(ushort4*)(base + CC)   = IS_A ? hi : lo;
    *(ushort4*)(base + 2*CC) = IS_A ? lo : hi;
}

// ---------------------------------------------------------------------------
// Split-bf16 MFMA GEMM, BK=64 (32 MFMA per barrier-pair, 36 iters).
// QKV_EPI: q,k -> split bf16 planes [B,H,N,hd]; v -> split bf16 TRANSPOSED
// planes vth/vtl [B,H,hd,N].  Else: out[m][NCOLS] + bias.
// ---------------------------------------------------------------------------
template<int NCOLS, bool QKV_EPI>
__global__ __launch_bounds__(256) void gemm_split(const unsigned short* __restrict__ A,
                                                  const unsigned short* __restrict__ Bm,
                                                  const float* __restrict__ bias,
                                                  float* __restrict__ out,
                                                  unsigned short* __restrict__ qh,
                                                  unsigned short* __restrict__ ql,
                                                  unsigned short* __restrict__ kh,
                                                  unsigned short* __restrict__ kl,
                                                  unsigned short* __restrict__ vth,
                                                  unsigned short* __restrict__ vtl) {
    __shared__ char lds[32768];          // A tile 16KB @0, B tile 16KB @16384
    const int bm = blockIdx.x, bn = blockIdx.y;
    const int tid  = threadIdx.x;
    const int wave = tid >> 6, lane = tid & 63;
    const int wm = wave >> 1, wn = wave & 1;
    const int quad = lane >> 4, r = lane & 15;

    // staging pointers: inst i, chunk c = tid + i*256 (c in [0,2048));
    // matrix = c>>10; s = c&1023; m = s>>3; octp = s&7; oct = octp ^ (m&7)
    const unsigned short* gbase[8];
#pragma unroll
    for (int i = 0; i < 8; ++i) {
        int c = tid + i*256;
        int s = c & 1023;
        int m = s >> 3, octp = s & 7, oct = octp ^ (m & 7);
        gbase[i] = (i < 4 ? A  + (size_t)(bm*128 + m) * KC
                          : Bm + (size_t)(bn*128 + m) * KC) + oct*8;
    }

    // fragment LDS offsets: row stored as 8 octets of 16B, oct = kslot ^ (row&7)
    int aoff[2][4], boff[2][4];
#pragma unroll
    for (int kb = 0; kb < 2; ++kb)
#pragma unroll
        for (int i = 0; i < 4; ++i) {
            int ra = wm*64 + i*16 + r;
            int rb2 = wn*64 + i*16 + r;
            aoff[kb][i] = (ra*8 + ((kb*4 + quad) ^ (ra & 7))) * 16;
            boff[kb][i] = 16384 + (rb2*8 + ((kb*4 + quad) ^ (rb2 & 7))) * 16;
        }

    floatx4 acc[4][4];
#pragma unroll
    for (int i = 0; i < 4; ++i)
#pragma unroll
        for (int j = 0; j < 4; ++j)
            acc[i][j] = (floatx4){0.f, 0.f, 0.f, 0.f};

    for (int it = 0; it < KC/64; ++it) {
        __syncthreads();
#pragma unroll
        for (int i = 0; i < 8; ++i) {
            __builtin_amdgcn_global_load_lds(
                (const __attribute__((address_space(1))) unsigned int*)gbase[i],
                (__attribute__((address_space(3))) unsigned int*)(lds + i*4096 + wave*1024),
                16, 0, 0);
            gbase[i] += 64;
        }
        asm volatile("s_waitcnt vmcnt(0)" ::: "memory");
        __syncthreads();

#pragma unroll
        for (int kb = 0; kb < 2; ++kb) {
            short8 af[4], bf[4];
#pragma unroll
            for (int i = 0; i < 4; ++i) af[i] = *(const short8*)(lds + aoff[kb][i]);
#pragma unroll
            for (int j = 0; j < 4; ++j) bf[j] = *(const short8*)(lds + boff[kb][j]);
#pragma unroll
            for (int i = 0; i < 4; ++i)
#pragma unroll
                for (int j = 0; j < 4; ++j)
                    acc[i][j] = __builtin_amdgcn_mfma_f32_16x16x32_bf16(af[i], bf[j], acc[i][j], 0, 0, 0);
        }
    }

    if (QKV_EPI) {
#pragma unroll
        for (int j = 0; j < 4; ++j) {
            int col = bn*128 + wn*64 + j*16 + r;     // [0,2304)
            int t = col / CC;
            int rem = col - t*CC;
            int h = rem >> 6, d = rem & 63;
            if (t == 2) {
                // v transposed split: vth/vtl[(bh*64+d)*512 + n], ushort4 over 4 rows
#pragma unroll
                for (int i = 0; i < 4; ++i) {
                    int m0 = bm*128 + wm*64 + i*16 + quad*4;
                    int b = m0 >> 9, n0 = m0 & 511;
                    ushort4 hi, lo;
                    hi.x = f2bf(acc[i][j][0]); lo.x = f2bf(acc[i][j][0] - bf2f(hi.x));
                    hi.y = f2bf(acc[i][j][1]); lo.y = f2bf(acc[i][j][1] - bf2f(hi.y));
                    hi.z = f2bf(acc[i][j][2]); lo.z = f2bf(acc[i][j][2] - bf2f(hi.z));
                    hi.w = f2bf(acc[i][j][3]); lo.w = f2bf(acc[i][j][3] - bf2f(hi.w));
                    size_t off = ((size_t)((b*HH + h)*HD + d))*NN + n0;
                    *(ushort4*)(vth + off) = hi;
                    *(ushort4*)(vtl + off) = lo;
                }
            } else {
                unsigned short* ph = (t == 0) ? qh : kh;
                unsigned short* pl = (t == 0) ? ql : kl;
#pragma unroll
                for (int i = 0; i < 4; ++i) {
#pragma unroll
                    for (int e = 0; e < 4; ++e) {
                        int m = bm*128 + wm*64 + i*16 + quad*4 + e;
                        int b = m >> 9, nrow = m & 511;
                        size_t idx = ((size_t)(b*HH + h)*NN + nrow)*HD + d;
                        float val = acc[i][j][e];
                        unsigned short hi = f2bf(val);
                        ph[idx] = hi;
                        pl[idx] = f2bf(val - bf2f(hi));
                    }
                }
            }
        }
    } else {
#pragma unroll
        for (int j = 0; j < 4; ++j) {
            int col = bn*128 + wn*64 + j*16 + r;
            float bv = bias[col];
#pragma unroll
            for (int i = 0; i < 4; ++i) {
#pragma unroll
                for (int e = 0; e < 4; ++e) {
                    int m = bm*128 + wm*64 + i*16 + quad*4 + e;
                    out[(size_t)m*NCOLS + col] = acc[i][j][e] + bv;
                }
            }
        }
    }
}

// ---------------------------------------------------------------------------
// FUSED: MFMA scores + exact top-k + softmax + PV.
// Phase 2: exact top-k via bit binary-search on the threshold:
// T* = max{T : count(key >= T) >= k}.  Per iteration only a count
// (cmp+addc per key) + one 16-lane shuffle-sum; no active-set mask,
// no or/and prefix init, no final min/max scan.  Early exit when
// count == k (mask-equivalent; ties descend to exact v_k).
// Everything else identical to the verified 115 us round-0 kernel
// (register-neutral: we sit at the 2-waves/SIMD unified-RF cliff).
// ---------------------------------------------------------------------------
__global__ __launch_bounds__(256, 1) void attn_scores_k(
        const unsigned short* __restrict__ qh, const unsigned short* __restrict__ ql,
        const unsigned short* __restrict__ kh, const unsigned short* __restrict__ kl,
        const unsigned short* __restrict__ vth, const unsigned short* __restrict__ vtl,
        const int* __restrict__ islast, float* __restrict__ attn,
        unsigned short* __restrict__ Ao) {

    __shared__ char smem[34816];
    // phase 0/1: qs = ushort[2][64][72] @0 (18432 B); ks @18432 (16384 B)
    // phase 3:   pls = ushort[64][80] @0 (10240 B); vhs @10240; vls @18432 (8192 each)
    unsigned short* qs = (unsigned short*)smem;
    char* ks = smem + 18432;

    const int bh = blockIdx.x % 96;
    const int rb = blockIdx.x / 96;
    const int tid = threadIdx.x;
    const int wv = tid >> 6, lane = tid & 63;
    const int quad = lane >> 4, r = lane & 15;
    const int b = bh / HH, h = bh % HH;

    const unsigned short* gq[2] = { qh + ((size_t)bh*NN + rb*64)*HD,
                                    ql + ((size_t)bh*NN + rb*64)*HD };
#pragma unroll
    for (int i = 0; i < 4; ++i) {
        int s = tid + i*256;
        int hl = s >> 9, s2 = s & 511;
        int row = s2 >> 3, oct = s2 & 7;
        short8 val = *(const short8*)(gq[hl] + row*HD + oct*8);
        *(short8*)&qs[(hl*64 + row)*72 + oct*8] = val;
    }
    __syncthreads();

    short8 afr[6];
    {
        const int arow = wv*16 + r;
#pragma unroll
        for (int t = 0; t < 3; ++t) {
            int src = (t == 2) ? 1 : 0;
#pragma unroll
            for (int half = 0; half < 2; ++half)
                afr[t*2+half] = *(const short8*)&qs[(src*64 + arow)*72 + half*32 + quad*8];
        }
    }

    floatx4 acc[32];
#pragma unroll
    for (int ct = 0; ct < 32; ++ct) acc[ct] = (floatx4){0.f,0.f,0.f,0.f};

    const unsigned short* gk[2] = { kh + (size_t)bh*NN*HD, kl + (size_t)bh*NN*HD };

    for (int ch = 0; ch < 8; ++ch) {
        __syncthreads();
#pragma unroll
        for (int i = 0; i < 4; ++i) {
            int s = tid + i*256;
            int hl = s >> 9, s2 = s & 511;
            int row = s2 >> 3, octp = s2 & 7;
            int oct = octp ^ (row & 7);
            const unsigned short* src = gk[hl] + (size_t)(ch*64 + row)*HD + oct*8;
            __builtin_amdgcn_global_load_lds(
                (const __attribute__((address_space(1))) unsigned int*)src,
                (__attribute__((address_space(3))) unsigned int*)(ks + (size_t)(i*256 + wv*64)*16),
                16, 0, 0);
        }
        asm volatile("s_waitcnt vmcnt(0)" ::: "memory");
        __syncthreads();

#pragma unroll
        for (int ctl = 0; ctl < 4; ++ctl) {
            const int ct = ch*4 + ctl;
            const int n = ctl*16 + r;
#pragma unroll
            for (int t = 0; t < 3; ++t) {
                const int srcB = (t == 1) ? 1 : 0;
#pragma unroll
                for (int half = 0; half < 2; ++half) {
                    const int oct = (half*4 + quad) ^ (n & 7);
                    short8 bfr = *(const short8*)(ks + srcB*8192 + n*128 + oct*16);
                    acc[ct] = __builtin_amdgcn_mfma_f32_16x16x32_bf16(afr[t*2+half], bfr, acc[ct], 0, 0, 0);
                }
            }
        }
    }

    const int lastv = islast[0];

    // ---- phase 2: per reg-row e: exact top-k (bit binary-search) + softmax ----
#pragma unroll
    for (int e = 0; e < 4; ++e) {
        unsigned int key[32];
#pragma unroll
        for (int ct = 0; ct < 32; ++ct) {
            unsigned int t = __float_as_uint(acc[ct][e] * 0.125f);
            key[ct] = (t & 0x80000000u) ? ~t : (t | 0x80000000u);
        }

        unsigned int kth = 0u;
        if (!lastv) {
            // binary search for T* = max{T : count(key >= T) >= TOPK}
            unsigned int T = 0u;
            int bit = 31, cc = 512, done = 0;
            while (__ballot(!done) != 0ull) {
                if (!done) {
                    unsigned int Tc = T | (1u << bit);
                    int c1 = 0;
#pragma unroll
                    for (int ct = 0; ct < 32; ++ct) c1 += (key[ct] >= Tc) ? 1 : 0;
                    c1 += __shfl_xor(c1, 1);
                    c1 += __shfl_xor(c1, 2);
                    c1 += __shfl_xor(c1, 4);
                    c1 += __shfl_xor(c1, 8);
                    if (c1 >= TOPK) { T = Tc; cc = c1; }
                    --bit;
                    done = (cc == TOPK) | (bit < 0);
                }
            }
            kth = T;
        }

        unsigned int umx = key[0];
#pragma unroll
        for (int ct = 1; ct < 32; ++ct) umx = umx > key[ct] ? umx : key[ct];
#pragma unroll
        for (int off = 1; off <= 8; off <<= 1) {
            unsigned int t2 = __shfl_xor(umx, off);
            umx = umx > t2 ? umx : t2;
        }
        float fmx = __uint_as_float((umx & 0x80000000u) ? (umx & 0x7FFFFFFFu) : ~umx);
        float sum = 0.f;
#pragma unroll
        for (int ct = 0; ct < 32; ++ct) {
            unsigned int uu = key[ct];
            float f = __uint_as_float((uu & 0x80000000u) ? (uu & 0x7FFFFFFFu) : ~uu);
            float ev = (lastv || uu >= kth) ? __expf(f - fmx) : 0.f;
            acc[ct][e] = ev;
            sum += ev;
        }
#pragma unroll
        for (int off = 1; off <= 8; off <<= 1) sum += __shfl_xor(sum, off);
        const float inv = 1.f / sum;
        float* arow = attn + ((size_t)bh*NN + rb*64 + wv*16 + quad*4 + e) * NN;
#pragma unroll
        for (int ct = 0; ct < 32; ++ct) {
            float p = acc[ct][e] * inv;
            acc[ct][e] = p;                  // keep normalized P in regs for PV
            arow[ct*16 + r] = p;
        }
    }

    // ---- phase 3: O = P @ V  (P in acc regs; 8 chunks of 64 K-cols) ----
    unsigned short* pls = (unsigned short*)smem;   // [64][80]
    char* vhs = smem + 10240;
    char* vls = smem + 18432;
    const unsigned short* gvh = vth + (size_t)bh*HD*NN;
    const unsigned short* gvl = vtl + (size_t)bh*HD*NN;

    floatx4 accO[4];
#pragma unroll
    for (int j = 0; j < 4; ++j) accO[j] = (floatx4){0.f,0.f,0.f,0.f};

    for (int ch = 0; ch < 8; ++ch) {
        __syncthreads();   // prev chunk reads done (first iter: phases 0-2 done)
        // write this wave's 16x64 P chunk as bf16 (C-layout -> [row][col])
#pragma unroll
        for (int ctl = 0; ctl < 4; ++ctl) {
            int col = ctl*16 + r;
#pragma unroll
            for (int e = 0; e < 4; ++e)
                pls[(wv*16 + quad*4 + e)*80 + col] = f2bf(acc[ch*4 + ctl][e]);
        }
        // stage V^T chunk (rows d=0..63, cols m=ch*64..+63), hi+lo planes
#pragma unroll
        for (int i = 0; i < 2; ++i) {
            int s = tid + i*256;
            int d = s >> 3, octp = s & 7, oct = octp ^ (d & 7);
            size_t goff = (size_t)d*NN + ch*64 + oct*8;
            __builtin_amdgcn_global_load_lds(
                (const __attribute__((address_space(1))) unsigned int*)(gvh + goff),
                (__attribute__((address_space(3))) unsigned int*)(vhs + (i*256 + wv*64)*16),
                16, 0, 0);
            __builtin_amdgcn_global_load_lds(
                (const __attribute__((address_space(1))) unsigned int*)(gvl + goff),
                (__attribute__((address_space(3))) unsigned int*)(vls + (i*256 + wv*64)*16),
                16, 0, 0);
        }
        asm volatile("s_waitcnt vmcnt(0)" ::: "memory");
        __syncthreads();

#pragma unroll
        for (int kb = 0; kb < 2; ++kb) {
            short8 af = *(const short8*)&pls[(wv*16 + r)*80 + kb*32 + quad*8];
#pragma unroll
            for (int j = 0; j < 4; ++j) {
                int d = j*16 + r;
                int oct = (kb*4 + quad) ^ (d & 7);
                short8 bh8 = *(const short8*)(vhs + d*128 + oct*16);
                short8 bl8 = *(const short8*)(vls + d*128 + oct*16);
                accO[j] = __builtin_amdgcn_mfma_f32_16x16x32_bf16(af, bh8, accO[j], 0, 0, 0);
                accO[j] = __builtin_amdgcn_mfma_f32_16x16x32_bf16(af, bl8, accO[j], 0, 0, 0);
            }
        }
    }

    // ---- epilogue: split-bf16 o [hi|hi|lo] into Ao ----
#pragma unroll
    for (int j = 0; j < 4; ++j) {
        int d = j*16 + r;
#pragma unroll
        for (int e = 0; e < 4; ++e) {
            int n = rb*64 + wv*16 + quad*4 + e;
            size_t mrow = (size_t)b*NN + n;
            float val = accO[j][e];
            unsigned short hi = f2bf(val);
            unsigned short lo = f2bf(val - bf2f(hi));
            unsigned short* base = Ao + mrow*KC + h*HD + d;
            base[0] = hi; base[CC] = hi; base[2*CC] = lo;
        }
    }
}

// ---------------------------------------------------------------------------
extern "C" void kernel_launch(void* const* d_in, const int* in_sizes, int n_in,
                              void* d_out, int out_size, void* d_ws, size_t ws_size,
                              hipStream_t stream) {
    const float* x      = (const float*)d_in[0];
    const float* qkv_w  = (const float*)d_in[1];
    const float* proj_w = (const float*)d_in[2];
    const float* proj_b = (const float*)d_in[3];
    const int*   islast = (const int*)d_in[4];

    float* out  = (float*)d_out;                       // [B,N,C]
    float* attn = out + (size_t)BB*NN*CC;              // [B,H,N,N]

    unsigned short* us = (unsigned short*)d_ws;
    unsigned short* vth = us;                          // [B,H,hd,N] bf16 hi
    unsigned short* vtl = vth + (size_t)QKV_ELEMS;     // [B,H,hd,N] bf16 lo
    unsigned short* qhp = vtl + (size_t)QKV_ELEMS;
    unsigned short* qlp = qhp + (size_t)QKV_ELEMS;
    unsigned short* khp = qlp + (size_t)QKV_ELEMS;
    unsigned short* klp = khp + (size_t)QKV_ELEMS;
    unsigned short* Asp   = klp + (size_t)QKV_ELEMS;   // [4096][2304]
    unsigned short* Bqkv  = Asp  + (size_t)4096*KC;    // [2304][2304]
    unsigned short* Bproj = Bqkv + (size_t)2304*KC;    // [768][2304]

    split_k<true> <<<dim3(4096*CC/4/256), 256, 0, stream>>>(x,      Asp,   4096*CC/4);
    split_k<false><<<dim3(2304*CC/4/256), 256, 0, stream>>>(qkv_w,  Bqkv,  2304*CC/4);
    split_k<false><<<dim3(CC*CC/4/256),   256, 0, stream>>>(proj_w, Bproj, CC*CC/4);

    gemm_split<0, true>  <<<dim3(32, 18), 256, 0, stream>>>(Asp, Bqkv, nullptr, nullptr,
                                                            qhp, qlp, khp, klp, vth, vtl);
    attn_scores_k        <<<dim3(96*8),   256, 0, stream>>>(qhp, qlp, khp, klp, vth, vtl,
                                                            islast, attn, Asp);
    gemm_split<CC, false><<<dim3(32, 6),  256, 0, stream>>>(Asp, Bproj, proj_b, out,
                                                            nullptr, nullptr, nullptr, nullptr,
                                                            nullptr, nullptr);
}

// Round 4
// 361.882 us; speedup vs baseline: 1.0234x; 1.0003x over previous
//
#include <hip/hip_runtime.h>
#include <math.h>

#define BB 8
#define NN 512
#define CC 768
#define HH 12
#define HD 64
#define TOPK 90
#define QKV_ELEMS (BB*HH*NN*HD)   // 3145728 elements per q/k/v tensor
#define KC 2304                   // split-K: 3*768

typedef __attribute__((ext_vector_type(8))) short short8;   // 8 bf16 = 4 VGPR
typedef __attribute__((ext_vector_type(4))) float floatx4;  // MFMA C/D

__device__ inline unsigned short f2bf(float f) {
    unsigned int u = __float_as_uint(f);
    u += 0x7FFFu + ((u >> 16) & 1u);           // RNE
    return (unsigned short)(u >> 16);
}
__device__ inline float bf2f(unsigned short h) {
    return __uint_as_float(((unsigned int)h) << 16);
}

// ---------------------------------------------------------------------------
// Split kernels: fp32 [rows][768] -> bf16 [rows][2304].
// IS_A: blocks [hi | hi | lo]; !IS_A: blocks [hi | lo | hi]  (hh+hl+lh).
// ---------------------------------------------------------------------------
template<bool IS_A>
__global__ __launch_bounds__(256) void split_k(const float* __restrict__ in,
                                               unsigned short* __restrict__ o2,
                                               int total) {
    int idx = blockIdx.x * 256 + threadIdx.x;
    if (idx >= total) return;
    int e = idx * 4;
    int m = e / CC, kk = e - m * CC;
    float4 f = *(const float4*)(in + e);
    ushort4 hi, lo;
    hi.x = f2bf(f.x); lo.x = f2bf(f.x - bf2f(hi.x));
    hi.y = f2bf(f.y); lo.y = f2bf(f.y - bf2f(hi.y));
    hi.z = f2bf(f.z); lo.z = f2bf(f.z - bf2f(hi.z));
    hi.w = f2bf(f.w); lo.w = f2bf(f.w - bf2f(hi.w));
    unsigned short* base = o2 + (size_t)m * KC + kk;
    *(ushort4*)(base)        = hi;
    *(ushort4*)(base + CC)   = IS_A ? hi : lo;
    *(ushort4*)(base + 2*CC) = IS_A ? lo : hi;
}

// ---------------------------------------------------------------------------
// Split-bf16 MFMA GEMM, BK=64 (32 MFMA per barrier-pair, 36 iters).
// QKV_EPI: q,k -> split bf16 planes [B,H,N,hd]; v -> split bf16 TRANSPOSED
// planes vth/vtl [B,H,hd,N].  Else: out[m][NCOLS] + bias.
// ---------------------------------------------------------------------------
template<int NCOLS, bool QKV_EPI>
__global__ __launch_bounds__(256) void gemm_split(const unsigned short* __restrict__ A,
                                                  const unsigned short* __restrict__ Bm,
                                                  const float* __restrict__ bias,
                                                  float* __restrict__ out,
                                                  unsigned short* __restrict__ qh,
                                                  unsigned short* __restrict__ ql,
                                                  unsigned short* __restrict__ kh,
                                                  unsigned short* __restrict__ kl,
                                                  unsigned short* __restrict__ vth,
                                                  unsigned short* __restrict__ vtl) {
    __shared__ char lds[32768];          // A tile 16KB @0, B tile 16KB @16384
    const int bm = blockIdx.x, bn = blockIdx.y;
    const int tid  = threadIdx.x;
    const int wave = tid >> 6, lane = tid & 63;
    const int wm = wave >> 1, wn = wave & 1;
    const int quad = lane >> 4, r = lane & 15;

    // staging pointers: inst i, chunk c = tid + i*256 (c in [0,2048));
    // matrix = c>>10; s = c&1023; m = s>>3; octp = s&7; oct = octp ^ (m&7)
    const unsigned short* gbase[8];
#pragma unroll
    for (int i = 0; i < 8; ++i) {
        int c = tid + i*256;
        int s = c & 1023;
        int m = s >> 3, octp = s & 7, oct = octp ^ (m & 7);
        gbase[i] = (i < 4 ? A  + (size_t)(bm*128 + m) * KC
                          : Bm + (size_t)(bn*128 + m) * KC) + oct*8;
    }

    // fragment LDS offsets: row stored as 8 octets of 16B, oct = kslot ^ (row&7)
    int aoff[2][4], boff[2][4];
#pragma unroll
    for (int kb = 0; kb < 2; ++kb)
#pragma unroll
        for (int i = 0; i < 4; ++i) {
            int ra = wm*64 + i*16 + r;
            int rb2 = wn*64 + i*16 + r;
            aoff[kb][i] = (ra*8 + ((kb*4 + quad) ^ (ra & 7))) * 16;
            boff[kb][i] = 16384 + (rb2*8 + ((kb*4 + quad) ^ (rb2 & 7))) * 16;
        }

    floatx4 acc[4][4];
#pragma unroll
    for (int i = 0; i < 4; ++i)
#pragma unroll
        for (int j = 0; j < 4; ++j)
            acc[i][j] = (floatx4){0.f, 0.f, 0.f, 0.f};

    for (int it = 0; it < KC/64; ++it) {
        __syncthreads();
#pragma unroll
        for (int i = 0; i < 8; ++i) {
            __builtin_amdgcn_global_load_lds(
                (const __attribute__((address_space(1))) unsigned int*)gbase[i],
                (__attribute__((address_space(3))) unsigned int*)(lds + i*4096 + wave*1024),
                16, 0, 0);
            gbase[i] += 64;
        }
        asm volatile("s_waitcnt vmcnt(0)" ::: "memory");
        __syncthreads();

#pragma unroll
        for (int kb = 0; kb < 2; ++kb) {
            short8 af[4], bf[4];
#pragma unroll
            for (int i = 0; i < 4; ++i) af[i] = *(const short8*)(lds + aoff[kb][i]);
#pragma unroll
            for (int j = 0; j < 4; ++j) bf[j] = *(const short8*)(lds + boff[kb][j]);
#pragma unroll
            for (int i = 0; i < 4; ++i)
#pragma unroll
                for (int j = 0; j < 4; ++j)
                    acc[i][j] = __builtin_amdgcn_mfma_f32_16x16x32_bf16(af[i], bf[j], acc[i][j], 0, 0, 0);
        }
    }

    if (QKV_EPI) {
#pragma unroll
        for (int j = 0; j < 4; ++j) {
            int col = bn*128 + wn*64 + j*16 + r;     // [0,2304)
            int t = col / CC;
            int rem = col - t*CC;
            int h = rem >> 6, d = rem & 63;
            if (t == 2) {
                // v transposed split: vth/vtl[(bh*64+d)*512 + n], ushort4 over 4 rows
#pragma unroll
                for (int i = 0; i < 4; ++i) {
                    int m0 = bm*128 + wm*64 + i*16 + quad*4;
                    int b = m0 >> 9, n0 = m0 & 511;
                    ushort4 hi, lo;
                    hi.x = f2bf(acc[i][j][0]); lo.x = f2bf(acc[i][j][0] - bf2f(hi.x));
                    hi.y = f2bf(acc[i][j][1]); lo.y = f2bf(acc[i][j][1] - bf2f(hi.y));
                    hi.z = f2bf(acc[i][j][2]); lo.z = f2bf(acc[i][j][2] - bf2f(hi.z));
                    hi.w = f2bf(acc[i][j][3]); lo.w = f2bf(acc[i][j][3] - bf2f(hi.w));
                    size_t off = ((size_t)((b*HH + h)*HD + d))*NN + n0;
                    *(ushort4*)(vth + off) = hi;
                    *(ushort4*)(vtl + off) = lo;
                }
            } else {
                unsigned short* ph = (t == 0) ? qh : kh;
                unsigned short* pl = (t == 0) ? ql : kl;
#pragma unroll
                for (int i = 0; i < 4; ++i) {
#pragma unroll
                    for (int e = 0; e < 4; ++e) {
                        int m = bm*128 + wm*64 + i*16 + quad*4 + e;
                        int b = m >> 9, nrow = m & 511;
                        size_t idx = ((size_t)(b*HH + h)*NN + nrow)*HD + d;
                        float val = acc[i][j][e];
                        unsigned short hi = f2bf(val);
                        ph[idx] = hi;
                        pl[idx] = f2bf(val - bf2f(hi));
                    }
                }
            }
        }
    } else {
#pragma unroll
        for (int j = 0; j < 4; ++j) {
            int col = bn*128 + wn*64 + j*16 + r;
            float bv = bias[col];
#pragma unroll
            for (int i = 0; i < 4; ++i) {
#pragma unroll
                for (int e = 0; e < 4; ++e) {
                    int m = bm*128 + wm*64 + i*16 + quad*4 + e;
                    out[(size_t)m*NCOLS + col] = acc[i][j][e] + bv;
                }
            }
        }
    }
}

// ---------------------------------------------------------------------------
// FUSED: MFMA scores + exact top-k + softmax + PV.
// Phase 2 (this round): e-PARALLEL restructure for ILP, register-neutral.
//  - the 4 per-e binary searches run in ONE loop (per-e T/done state, shared
//    uniform bit) -> 4 independent count+reduce chains overlap instead of
//    running back-to-back (previous rounds were chain-latency-bound).
//  - search compares acc floats directly against the decoded candidate
//    threshold (3 ops/iter), deleting key[32] and all key build/decode.
//    Float-domain ">=" matches the reference's `attn >= kth` exactly.
//  - tree-structured counts (4 partials) cut chain depth 32 -> ~10.
//  - max/exp/sum chains also interleaved across e.
// ---------------------------------------------------------------------------
__global__ __launch_bounds__(256, 1) void attn_scores_k(
        const unsigned short* __restrict__ qh, const unsigned short* __restrict__ ql,
        const unsigned short* __restrict__ kh, const unsigned short* __restrict__ kl,
        const unsigned short* __restrict__ vth, const unsigned short* __restrict__ vtl,
        const int* __restrict__ islast, float* __restrict__ attn,
        unsigned short* __restrict__ Ao) {

    __shared__ char smem[34816];
    // phase 0/1: qs = ushort[2][64][72] @0 (18432 B); ks @18432 (16384 B)
    // phase 3:   pls = ushort[64][80] @0 (10240 B); vhs @10240; vls @18432 (8192 each)
    unsigned short* qs = (unsigned short*)smem;
    char* ks = smem + 18432;

    const int bh = blockIdx.x % 96;
    const int rb = blockIdx.x / 96;
    const int tid = threadIdx.x;
    const int wv = tid >> 6, lane = tid & 63;
    const int quad = lane >> 4, r = lane & 15;
    const int b = bh / HH, h = bh % HH;

    const unsigned short* gq[2] = { qh + ((size_t)bh*NN + rb*64)*HD,
                                    ql + ((size_t)bh*NN + rb*64)*HD };
#pragma unroll
    for (int i = 0; i < 4; ++i) {
        int s = tid + i*256;
        int hl = s >> 9, s2 = s & 511;
        int row = s2 >> 3, oct = s2 & 7;
        short8 val = *(const short8*)(gq[hl] + row*HD + oct*8);
        *(short8*)&qs[(hl*64 + row)*72 + oct*8] = val;
    }
    __syncthreads();

    short8 afr[6];
    {
        const int arow = wv*16 + r;
#pragma unroll
        for (int t = 0; t < 3; ++t) {
            int src = (t == 2) ? 1 : 0;
#pragma unroll
            for (int half = 0; half < 2; ++half)
                afr[t*2+half] = *(const short8*)&qs[(src*64 + arow)*72 + half*32 + quad*8];
        }
    }

    floatx4 acc[32];
#pragma unroll
    for (int ct = 0; ct < 32; ++ct) acc[ct] = (floatx4){0.f,0.f,0.f,0.f};

    const unsigned short* gk[2] = { kh + (size_t)bh*NN*HD, kl + (size_t)bh*NN*HD };

    for (int ch = 0; ch < 8; ++ch) {
        __syncthreads();
#pragma unroll
        for (int i = 0; i < 4; ++i) {
            int s = tid + i*256;
            int hl = s >> 9, s2 = s & 511;
            int row = s2 >> 3, octp = s2 & 7;
            int oct = octp ^ (row & 7);
            const unsigned short* src = gk[hl] + (size_t)(ch*64 + row)*HD + oct*8;
            __builtin_amdgcn_global_load_lds(
                (const __attribute__((address_space(1))) unsigned int*)src,
                (__attribute__((address_space(3))) unsigned int*)(ks + (size_t)(i*256 + wv*64)*16),
                16, 0, 0);
        }
        asm volatile("s_waitcnt vmcnt(0)" ::: "memory");
        __syncthreads();

#pragma unroll
        for (int ctl = 0; ctl < 4; ++ctl) {
            const int ct = ch*4 + ctl;
            const int n = ctl*16 + r;
#pragma unroll
            for (int t = 0; t < 3; ++t) {
                const int srcB = (t == 1) ? 1 : 0;
#pragma unroll
                for (int half = 0; half < 2; ++half) {
                    const int oct = (half*4 + quad) ^ (n & 7);
                    short8 bfr = *(const short8*)(ks + srcB*8192 + n*128 + oct*16);
                    acc[ct] = __builtin_amdgcn_mfma_f32_16x16x32_bf16(afr[t*2+half], bfr, acc[ct], 0, 0, 0);
                }
            }
        }
    }

    const int lastv = islast[0];

    // ---- phase 2: e-parallel exact top-k + softmax ----
    // Row max per e (4 independent chains; 4 partials each).
    float fmx4[4], sum4[4], kthf4[4];
#pragma unroll
    for (int e = 0; e < 4; ++e) {
        float m0 = acc[0][e], m1 = acc[1][e], m2 = acc[2][e], m3 = acc[3][e];
#pragma unroll
        for (int ct = 4; ct < 32; ct += 4) {
            m0 = fmaxf(m0, acc[ct  ][e]); m1 = fmaxf(m1, acc[ct+1][e]);
            m2 = fmaxf(m2, acc[ct+2][e]); m3 = fmaxf(m3, acc[ct+3][e]);
        }
        fmx4[e] = fmaxf(fmaxf(m0, m1), fmaxf(m2, m3));
    }
#pragma unroll
    for (int off = 1; off <= 8; off <<= 1)
#pragma unroll
        for (int e = 0; e < 4; ++e)
            fmx4[e] = fmaxf(fmx4[e], __shfl_xor(fmx4[e], off));

#pragma unroll
    for (int e = 0; e < 4; ++e) kthf4[e] = -INFINITY;

    if (!lastv) {
        // Combined bit binary-search, float-domain compares.
        // T* (key space) = max{T : count(f >= invkey(T)) >= TOPK}; invkey is
        // the inverse of the standard order-preserving float->uint map.
        unsigned int T[4] = {0u, 0u, 0u, 0u};
        int done[4] = {0, 0, 0, 0};
        for (int bit = 31; bit >= 0; --bit) {
            if (__ballot(!(done[0] & done[1] & done[2] & done[3])) == 0ull) break;
            const unsigned int bm = 1u << bit;
#pragma unroll
            for (int e = 0; e < 4; ++e) {
                const unsigned int Tc = T[e] | bm;
                const float fTc = __uint_as_float(
                    (Tc & 0x80000000u) ? (Tc & 0x7FFFFFFFu) : ~Tc);
                int p0 = 0, p1 = 0, p2 = 0, p3 = 0;
#pragma unroll
                for (int ct = 0; ct < 32; ct += 4) {
                    p0 += (acc[ct  ][e] >= fTc) ? 1 : 0;
                    p1 += (acc[ct+1][e] >= fTc) ? 1 : 0;
                    p2 += (acc[ct+2][e] >= fTc) ? 1 : 0;
                    p3 += (acc[ct+3][e] >= fTc) ? 1 : 0;
                }
                int c = (p0 + p1) + (p2 + p3);
                c += __shfl_xor(c, 1);
                c += __shfl_xor(c, 2);
                c += __shfl_xor(c, 4);
                c += __shfl_xor(c, 8);
                const bool acceptb = (c >= TOPK) && !done[e];
                T[e] = acceptb ? Tc : T[e];
                done[e] = (acceptb && c == TOPK) ? 1 : done[e];
            }
        }
#pragma unroll
        for (int e = 0; e < 4; ++e)
            kthf4[e] = __uint_as_float(
                (T[e] & 0x80000000u) ? (T[e] & 0x7FFFFFFFu) : ~T[e]);
    }

    // exp + per-lane sums (4 partials, chains interleaved across e)
#pragma unroll
    for (int e = 0; e < 4; ++e) {
        const float fm = fmx4[e], kf = kthf4[e];
        float s0 = 0.f, s1 = 0.f, s2 = 0.f, s3 = 0.f;
#pragma unroll
        for (int ct = 0; ct < 32; ct += 4) {
            float f0 = acc[ct  ][e], f1 = acc[ct+1][e];
            float f2 = acc[ct+2][e], f3 = acc[ct+3][e];
            float v0 = (f0 >= kf) ? __expf((f0 - fm) * 0.125f) : 0.f;
            float v1 = (f1 >= kf) ? __expf((f1 - fm) * 0.125f) : 0.f;
            float v2 = (f2 >= kf) ? __expf((f2 - fm) * 0.125f) : 0.f;
            float v3 = (f3 >= kf) ? __expf((f3 - fm) * 0.125f) : 0.f;
            acc[ct  ][e] = v0; acc[ct+1][e] = v1;
            acc[ct+2][e] = v2; acc[ct+3][e] = v3;
            s0 += v0; s1 += v1; s2 += v2; s3 += v3;
        }
        sum4[e] = (s0 + s1) + (s2 + s3);
    }
#pragma unroll
    for (int off = 1; off <= 8; off <<= 1)
#pragma unroll
        for (int e = 0; e < 4; ++e)
            sum4[e] += __shfl_xor(sum4[e], off);

#pragma unroll
    for (int e = 0; e < 4; ++e) {
        const float inv = 1.f / sum4[e];
        float* arow = attn + ((size_t)bh*NN + rb*64 + wv*16 + quad*4 + e) * NN;
#pragma unroll
        for (int ct = 0; ct < 32; ++ct) {
            float p = acc[ct][e] * inv;
            acc[ct][e] = p;                  // keep normalized P in regs for PV
            arow[ct*16 + r] = p;
        }
    }

    // ---- phase 3: O = P @ V  (P in acc regs; 8 chunks of 64 K-cols) ----
    unsigned short* pls = (unsigned short*)smem;   // [64][80]
    char* vhs = smem + 10240;
    char* vls = smem + 18432;
    const unsigned short* gvh = vth + (size_t)bh*HD*NN;
    const unsigned short* gvl = vtl + (size_t)bh*HD*NN;

    floatx4 accO[4];
#pragma unroll
    for (int j = 0; j < 4; ++j) accO[j] = (floatx4){0.f,0.f,0.f,0.f};

    for (int ch = 0; ch < 8; ++ch) {
        __syncthreads();   // prev chunk reads done (first iter: phases 0-2 done)
        // write this wave's 16x64 P chunk as bf16 (C-layout -> [row][col])
#pragma unroll
        for (int ctl = 0; ctl < 4; ++ctl) {
            int col = ctl*16 + r;
#pragma unroll
            for (int e = 0; e < 4; ++e)
                pls[(wv*16 + quad*4 + e)*80 + col] = f2bf(acc[ch*4 + ctl][e]);
        }
        // stage V^T chunk (rows d=0..63, cols m=ch*64..+63), hi+lo planes
#pragma unroll
        for (int i = 0; i < 2; ++i) {
            int s = tid + i*256;
            int d = s >> 3, octp = s & 7, oct = octp ^ (d & 7);
            size_t goff = (size_t)d*NN + ch*64 + oct*8;
            __builtin_amdgcn_global_load_lds(
                (const __attribute__((address_space(1))) unsigned int*)(gvh + goff),
                (__attribute__((address_space(3))) unsigned int*)(vhs + (i*256 + wv*64)*16),
                16, 0, 0);
            __builtin_amdgcn_global_load_lds(
                (const __attribute__((address_space(1))) unsigned int*)(gvl + goff),
                (__attribute__((address_space(3))) unsigned int*)(vls + (i*256 + wv*64)*16),
                16, 0, 0);
        }
        asm volatile("s_waitcnt vmcnt(0)" ::: "memory");
        __syncthreads();

#pragma unroll
        for (int kb = 0; kb < 2; ++kb) {
            short8 af = *(const short8*)&pls[(wv*16 + r)*80 + kb*32 + quad*8];
#pragma unroll
            for (int j = 0; j < 4; ++j) {
                int d = j*16 + r;
                int oct = (kb*4 + quad) ^ (d & 7);
                short8 bh8 = *(const short8*)(vhs + d*128 + oct*16);
                short8 bl8 = *(const short8*)(vls + d*128 + oct*16);
                accO[j] = __builtin_amdgcn_mfma_f32_16x16x32_bf16(af, bh8, accO[j], 0, 0, 0);
                accO[j] = __builtin_amdgcn_mfma_f32_16x16x32_bf16(af, bl8, accO[j], 0, 0, 0);
            }
        }
    }

    // ---- epilogue: split-bf16 o [hi|hi|lo] into Ao ----
#pragma unroll
    for (int j = 0; j < 4; ++j) {
        int d = j*16 + r;
#pragma unroll
        for (int e = 0; e < 4; ++e) {
            int n = rb*64 + wv*16 + quad*4 + e;
            size_t mrow = (size_t)b*NN + n;
            float val = accO[j][e];
            unsigned short hi = f2bf(val);
            unsigned short lo = f2bf(val - bf2f(hi));
            unsigned short* base = Ao + mrow*KC + h*HD + d;
            base[0] = hi; base[CC] = hi; base[2*CC] = lo;
        }
    }
}

// ---------------------------------------------------------------------------
extern "C" void kernel_launch(void* const* d_in, const int* in_sizes, int n_in,
                              void* d_out, int out_size, void* d_ws, size_t ws_size,
                              hipStream_t stream) {
    const float* x      = (const float*)d_in[0];
    const float* qkv_w  = (const float*)d_in[1];
    const float* proj_w = (const float*)d_in[2];
    const float* proj_b = (const float*)d_in[3];
    const int*   islast = (const int*)d_in[4];

    float* out  = (float*)d_out;                       // [B,N,C]
    float* attn = out + (size_t)BB*NN*CC;              // [B,H,N,N]

    unsigned short* us = (unsigned short*)d_ws;
    unsigned short* vth = us;                          // [B,H,hd,N] bf16 hi
    unsigned short* vtl = vth + (size_t)QKV_ELEMS;     // [B,H,hd,N] bf16 lo
    unsigned short* qhp = vtl + (size_t)QKV_ELEMS;
    unsigned short* qlp = qhp + (size_t)QKV_ELEMS;
    unsigned short* khp = qlp + (size_t)QKV_ELEMS;
    unsigned short* klp = khp + (size_t)QKV_ELEMS;
    unsigned short* Asp   = klp + (size_t)QKV_ELEMS;   // [4096][2304]
    unsigned short* Bqkv  = Asp  + (size_t)4096*KC;    // [2304][2304]
    unsigned short* Bproj = Bqkv + (size_t)2304*KC;    // [768][2304]

    split_k<true> <<<dim3(4096*CC/4/256), 256, 0, stream>>>(x,      Asp,   4096*CC/4);
    split_k<false><<<dim3(2304*CC/4/256), 256, 0, stream>>>(qkv_w,  Bqkv,  2304*CC/4);
    split_k<false><<<dim3(CC*CC/4/256),   256, 0, stream>>>(proj_w, Bproj, CC*CC/4);

    gemm_split<0, true>  <<<dim3(32, 18), 256, 0, stream>>>(Asp, Bqkv, nullptr, nullptr,
                                                            qhp, qlp, khp, klp, vth, vtl);
    attn_scores_k        <<<dim3(96*8),   256, 0, stream>>>(qhp, qlp, khp, klp, vth, vtl,
                                                            islast, attn, Asp);
    gemm_split<CC, false><<<dim3(32, 6),  256, 0, stream>>>(Asp, Bproj, proj_b, out,
                                                            nullptr, nullptr, nullptr, nullptr,
                                                            nullptr, nullptr);
}